// Round 6
// baseline (312.049 us; speedup 1.0000x reference)
//
#include <hip/hip_runtime.h>
#include <hip/hip_bf16.h>

#define B_TOT 16384
#define C_CH  64
#define F_IN  128
#define H_HID 128
#define ROWS  512      // rows per block; 4 waves x 8 sub-chunks x 16 rows
#define NSUB  8        // sub-chunks per wave

using f32x4  = __attribute__((ext_vector_type(4))) float;
using bf16x8 = __attribute__((ext_vector_type(8))) short;

__device__ inline unsigned pack2(float a, float b) {
    unsigned short lo = __builtin_bit_cast(unsigned short, __float2bfloat16(a));
    unsigned short hi = __builtin_bit_cast(unsigned short, __float2bfloat16(b));
    return (unsigned)lo | ((unsigned)hi << 16);
}

// issue the 8 float4 loads for one 16-row sub-chunk (8 KB/wave in flight)
__device__ inline void load_sub(const float* __restrict__ X, int rbase, int c,
                                int l15, int lg, float4 (&r)[8]) {
    const float* xb = X + ((size_t)(rbase + l15) * C_CH + c) * F_IN + lg * 8;
    #pragma unroll
    for (int ks = 0; ks < 4; ++ks) {
        r[ks * 2]     = *reinterpret_cast<const float4*>(xb + ks * 32);
        r[ks * 2 + 1] = *reinterpret_cast<const float4*>(xb + ks * 32 + 4);
    }
}

__device__ inline void compute_sub(const char* ws, const float4 (&r)[8],
                                   const float (&w2v)[8], const float (&b1v)[8],
                                   float b2c, int rbase, int l15, int lg,
                                   float* __restrict__ out)
{
    f32x4 acc[8];
    #pragma unroll
    for (int nf = 0; nf < 8; ++nf) acc[nf] = f32x4{0.f, 0.f, 0.f, 0.f};

    #pragma unroll
    for (int ks = 0; ks < 4; ++ks) {
        const int kbyte = ks * 64 + lg * 16;
        float4 r0 = r[ks * 2], r1 = r[ks * 2 + 1];
        uint4 pa;
        pa.x = pack2(r0.x, r0.y);
        pa.y = pack2(r0.z, r0.w);
        pa.z = pack2(r1.x, r1.y);
        pa.w = pack2(r1.z, r1.w);
        bf16x8 a = __builtin_bit_cast(bf16x8, pa);
        #pragma unroll
        for (int nf = 0; nf < 8; ++nf) {
            int n = nf * 16 + l15;
            bf16x8 b = *reinterpret_cast<const bf16x8*>(
                ws + n * 256 + (kbyte ^ ((n & 7) << 4)));
            acc[nf] = __builtin_amdgcn_mfma_f32_16x16x32_bf16(a, b, acc[nf], 0, 0, 0);
        }
    }

    // relu(+b1), dot W2, 16-lane col reduce, one atomic per row
    float part[4] = {0.f, 0.f, 0.f, 0.f};
    #pragma unroll
    for (int nf = 0; nf < 8; ++nf)
        #pragma unroll
        for (int j = 0; j < 4; ++j)
            part[j] += fmaxf(acc[nf][j] + b1v[nf], 0.f) * w2v[nf];
    #pragma unroll
    for (int off = 8; off >= 1; off >>= 1)
        #pragma unroll
        for (int j = 0; j < 4; ++j)
            part[j] += __shfl_xor(part[j], off, 64);
    if (l15 == 0) {
        int row = rbase + lg * 4;
        #pragma unroll
        for (int j = 0; j < 4; ++j)
            atomicAdd(&out[row + j], part[j] + b2c);
    }
}

// min 3 waves/EU -> VGPR capped at ~168 -> 12 waves/CU (was 8 at cap 256).
// Live-set estimate ~160: rA/rB 64 + acc 32 + b-temps ~32 + w2v/b1v 16 + addr.
__global__ __launch_bounds__(256, 3)
void fused_mlp_kernel(const float* __restrict__ X,
                      const float* __restrict__ W1,
                      const float* __restrict__ b1,
                      const float* __restrict__ W2,
                      const float* __restrict__ b2,
                      float* __restrict__ out)
{
    __shared__ short Ws[H_HID * F_IN];   // W1_c bf16 [n][k], XOR-swizzled

    const int t    = threadIdx.x;
    const int lane = t & 63;
    const int wave = t >> 6;
    // channel-major grid (r3 — best so far; r5's XCD-stripe swizzle regressed)
    const int c    = blockIdx.x;
    const int m0   = blockIdx.y * ROWS;

    char* ws = reinterpret_cast<char*>(Ws);

    const int l15 = lane & 15;
    const int lg  = lane >> 4;

    // hoist first X prefetch above W1 staging: LDS-independent, hides startup
    float4 rA[8], rB[8];
    load_sub(X, m0 + wave * 16, c, l15, lg, rA);

    // ---- stage W1_c transposed to [n][k]: coalesced along n ----
    {
        const int n  = t & 127;
        const int kh = (t >> 7) * 64;
        const float* wbase = W1 + (size_t)c * F_IN * H_HID + n;
        #pragma unroll
        for (int kk = 0; kk < 64; kk += 8) {
            float f[8];
            #pragma unroll
            for (int j = 0; j < 8; ++j)
                f[j] = wbase[(size_t)(kh + kk + j) * H_HID];
            uint4 p;
            p.x = pack2(f[0], f[1]);
            p.y = pack2(f[2], f[3]);
            p.z = pack2(f[4], f[5]);
            p.w = pack2(f[6], f[7]);
            int byte = ((kh + kk) * 2) ^ ((n & 7) << 4);
            *reinterpret_cast<uint4*>(ws + n * 256 + byte) = p;
        }
    }

    float w2v[8], b1v[8];
    #pragma unroll
    for (int nf = 0; nf < 8; ++nf) {
        w2v[nf] = W2[c * H_HID + nf * 16 + l15];
        b1v[nf] = b1[c * H_HID + nf * 16 + l15];
    }
    const float b2c = b2[c];

    __syncthreads();

    // ---- depth-1 ping-pong (r3 structure) ----
    #pragma unroll 1
    for (int sc = 0; sc < NSUB; sc += 2) {
        const int rbA = m0 + (sc * 4 + wave) * 16;
        const int rbB = m0 + ((sc + 1) * 4 + wave) * 16;
        load_sub(X, rbB, c, l15, lg, rB);                 // prefetch sc+1
        compute_sub(ws, rA, w2v, b1v, b2c, rbA, l15, lg, out);
        if (sc + 2 < NSUB)
            load_sub(X, m0 + ((sc + 2) * 4 + wave) * 16, c, l15, lg, rA);
        compute_sub(ws, rB, w2v, b1v, b2c, rbB, l15, lg, out);
    }
}

extern "C" void kernel_launch(void* const* d_in, const int* in_sizes, int n_in,
                              void* d_out, int out_size, void* d_ws, size_t ws_size,
                              hipStream_t stream) {
    const float* X  = (const float*)d_in[0];   // [B, C, F]
    const float* W1 = (const float*)d_in[1];   // [C, F, H]
    const float* b1 = (const float*)d_in[2];   // [C, H]
    const float* W2 = (const float*)d_in[3];   // [C, H]
    const float* b2 = (const float*)d_in[4];   // [C]
    float* out = (float*)d_out;                // [B]

    // atomics accumulate into out -> must zero it every call (d_out is poisoned)
    hipMemsetAsync(out, 0, (size_t)out_size * sizeof(float), stream);

    dim3 grid(C_CH, B_TOT / ROWS);   // channel-major
    fused_mlp_kernel<<<grid, dim3(256), 0, stream>>>(X, W1, b1, W2, b2, out);
}

// Round 7
// 184.047 us; speedup vs baseline: 1.6955x; 1.6955x over previous
//
#include <hip/hip_runtime.h>
#include <hip/hip_bf16.h>

#define B_TOT 16384
#define C_CH  64
#define F_IN  128
#define H_HID 128
#define ROWS  512      // rows per block; 4 waves x 8 sub-chunks x 16 rows
#define NSUB  8        // sub-chunks per wave

using f32x4  = __attribute__((ext_vector_type(4))) float;
using bf16x8 = __attribute__((ext_vector_type(8))) short;

__device__ inline unsigned pack2(float a, float b) {
    unsigned short lo = __builtin_bit_cast(unsigned short, __float2bfloat16(a));
    unsigned short hi = __builtin_bit_cast(unsigned short, __float2bfloat16(b));
    return (unsigned)lo | ((unsigned)hi << 16);
}

// issue the 8 float4 loads for one 16-row sub-chunk (8 KB/wave in flight)
__device__ inline void load_sub(const float* __restrict__ X, int rbase, int c,
                                int l15, int lg, float4 (&r)[8]) {
    const float* xb = X + ((size_t)(rbase + l15) * C_CH + c) * F_IN + lg * 8;
    #pragma unroll
    for (int ks = 0; ks < 4; ++ks) {
        r[ks * 2]     = *reinterpret_cast<const float4*>(xb + ks * 32);
        r[ks * 2 + 1] = *reinterpret_cast<const float4*>(xb + ks * 32 + 4);
    }
}

// Swapped-operand MFMA: D = W1tile(A, m=h) x Xtile(B, n=batchrow).
// A-frag = same Ws read as before; B-frag = same X registers as before.
// Output: acc[nf][j] <-> batchrow = l15, h = nf*16 + lg*4 + j  -> the
// relu+W2 reduction over h is 32 in-lane values + 2 shuffles (was 16
// DS-shuffles, depth 4). b1 rides in as the MFMA C-input.
__device__ inline float compute_sub(const char* ws, const float4 (&r)[8],
                                    const f32x4 (&w2c)[8], const f32x4 (&b1c)[8],
                                    int l15, int lg)
{
    f32x4 acc[8];
    #pragma unroll
    for (int nf = 0; nf < 8; ++nf) acc[nf] = b1c[nf];

    #pragma unroll
    for (int ks = 0; ks < 4; ++ks) {
        const int kbyte = ks * 64 + lg * 16;
        float4 r0 = r[ks * 2], r1 = r[ks * 2 + 1];
        uint4 px;
        px.x = pack2(r0.x, r0.y);
        px.y = pack2(r0.z, r0.w);
        px.z = pack2(r1.x, r1.y);
        px.w = pack2(r1.z, r1.w);
        bf16x8 xfrag = __builtin_bit_cast(bf16x8, px);
        #pragma unroll
        for (int nf = 0; nf < 8; ++nf) {
            int n = nf * 16 + l15;
            bf16x8 wfrag = *reinterpret_cast<const bf16x8*>(
                ws + n * 256 + (kbyte ^ ((n & 7) << 4)));
            acc[nf] = __builtin_amdgcn_mfma_f32_16x16x32_bf16(
                wfrag, xfrag, acc[nf], 0, 0, 0);   // swapped order
        }
    }

    float part = 0.f;
    #pragma unroll
    for (int nf = 0; nf < 8; ++nf)
        #pragma unroll
        for (int j = 0; j < 4; ++j)
            part += fmaxf(acc[nf][j], 0.f) * w2c[nf][j];
    // sum the 4 lg-groups (h-quarters); rows are lane-local (l15)
    part += __shfl_xor(part, 16, 64);
    part += __shfl_xor(part, 32, 64);
    return part;
}

__global__ __launch_bounds__(256, 2)
void fused_mlp_kernel(const float* __restrict__ X,
                      const float* __restrict__ W1,
                      const float* __restrict__ b1,
                      const float* __restrict__ W2,
                      const float* __restrict__ b2,
                      float* __restrict__ out)
{
    __shared__ short Ws[H_HID * F_IN];   // W1_c bf16 [n][k], XOR-swizzled

    const int t    = threadIdx.x;
    const int lane = t & 63;
    const int wave = t >> 6;
    // channel-major grid (r3 best; r5 XCD-stripe and r6 occupancy both regressed)
    const int c    = blockIdx.x;
    const int m0   = blockIdx.y * ROWS;

    char* ws = reinterpret_cast<char*>(Ws);

    const int l15 = lane & 15;
    const int lg  = lane >> 4;

    // hoist first X prefetch above W1 staging: LDS-independent, hides startup
    float4 rA[8], rB[8];
    load_sub(X, m0 + wave * 16, c, l15, lg, rA);

    // ---- stage W1_c transposed to [n][k]: coalesced along n ----
    {
        const int n  = t & 127;
        const int kh = (t >> 7) * 64;
        const float* wbase = W1 + (size_t)c * F_IN * H_HID + n;
        #pragma unroll
        for (int kk = 0; kk < 64; kk += 8) {
            float f[8];
            #pragma unroll
            for (int j = 0; j < 8; ++j)
                f[j] = wbase[(size_t)(kh + kk + j) * H_HID];
            uint4 p;
            p.x = pack2(f[0], f[1]);
            p.y = pack2(f[2], f[3]);
            p.z = pack2(f[4], f[5]);
            p.w = pack2(f[6], f[7]);
            int byte = ((kh + kk) * 2) ^ ((n & 7) << 4);
            *reinterpret_cast<uint4*>(ws + n * 256 + byte) = p;
        }
    }

    // per-lane h-constants: h = nf*16 + lg*4 + j  (float4 broadcast loads)
    f32x4 w2c[8], b1c[8];
    #pragma unroll
    for (int nf = 0; nf < 8; ++nf) {
        w2c[nf] = *reinterpret_cast<const f32x4*>(W2 + c * H_HID + nf * 16 + lg * 4);
        b1c[nf] = *reinterpret_cast<const f32x4*>(b1 + c * H_HID + nf * 16 + lg * 4);
    }
    const float b2c = b2[c];

    __syncthreads();

    // ---- depth-1 ping-pong (r3 structure) ----
    #pragma unroll 1
    for (int sc = 0; sc < NSUB; sc += 2) {
        const int rbA = m0 + (sc * 4 + wave) * 16;
        const int rbB = m0 + ((sc + 1) * 4 + wave) * 16;
        load_sub(X, rbB, c, l15, lg, rB);                 // prefetch sc+1
        float pA = compute_sub(ws, rA, w2c, b1c, l15, lg);
        if (lg == 0) atomicAdd(&out[rbA + l15], pA + b2c);
        if (sc + 2 < NSUB)
            load_sub(X, m0 + ((sc + 2) * 4 + wave) * 16, c, l15, lg, rA);
        float pB = compute_sub(ws, rB, w2c, b1c, l15, lg);
        if (lg == 0) atomicAdd(&out[rbB + l15], pB + b2c);
    }
}

extern "C" void kernel_launch(void* const* d_in, const int* in_sizes, int n_in,
                              void* d_out, int out_size, void* d_ws, size_t ws_size,
                              hipStream_t stream) {
    const float* X  = (const float*)d_in[0];   // [B, C, F]
    const float* W1 = (const float*)d_in[1];   // [C, F, H]
    const float* b1 = (const float*)d_in[2];   // [C, H]
    const float* W2 = (const float*)d_in[3];   // [C, H]
    const float* b2 = (const float*)d_in[4];   // [C]
    float* out = (float*)d_out;                // [B]

    // atomics accumulate into out -> must zero it every call (d_out is poisoned)
    hipMemsetAsync(out, 0, (size_t)out_size * sizeof(float), stream);

    dim3 grid(C_CH, B_TOT / ROWS);   // channel-major
    fused_mlp_kernel<<<grid, dim3(256), 0, stream>>>(X, W1, b1, W2, b2, out);
}

// Round 8
// 130.047 us; speedup vs baseline: 2.3995x; 1.4152x over previous
//
#include <hip/hip_runtime.h>
#include <hip/hip_bf16.h>

#define B_TOT 16384
#define C_CH  64
#define F_IN  128
#define H_HID 128
#define ROWS  1024     // rows per block; 4 waves x 16 rounds x 16 rows
#define NSUB  16       // rounds per wave

using f32x4  = __attribute__((ext_vector_type(4))) float;
using bf16x8 = __attribute__((ext_vector_type(8))) short;

__device__ inline unsigned pack2(float a, float b) {
    unsigned short lo = __builtin_bit_cast(unsigned short, __float2bfloat16(a));
    unsigned short hi = __builtin_bit_cast(unsigned short, __float2bfloat16(b));
    return (unsigned)lo | ((unsigned)hi << 16);
}

// async global->LDS, 16B per lane; LDS dest = uniform base + lane*16 (HW rule)
__device__ inline void gld_lds16(const float* g, float* l) {
    __builtin_amdgcn_global_load_lds(
        (const __attribute__((address_space(1))) void*)g,
        (__attribute__((address_space(3))) void*)l, 16, 0, 0);
}

// Stage one 16-row x 512B X tile into this wave's LDS buffer (8 vm ops).
// Instr j: lane l -> row (l&15), floats [j*16 + (l>>4)*4, +4).
// LDS layout: float offset = j*256 + l*16/4  (linear in lane order).
__device__ inline void issue_tile(const float* __restrict__ X, int rbase, int c,
                                  int lane, float* xbuf) {
    const float* g = X + ((size_t)(rbase + (lane & 15)) * C_CH + c) * F_IN
                       + (lane >> 4) * 4;
    #pragma unroll
    for (int j = 0; j < 8; ++j)
        gld_lds16(g + j * 16, xbuf + j * 256);
}

// One 16-row round: wait tile retired (vmcnt<=N, counted - never 0), ds_read
// fp32, pack bf16, 32 MFMA, relu+W2 dot, butterfly+gather. Returns the value
// lane L<16 must atomically add to out[rbase+L].
template<int N>
__device__ inline float compute_round(const float* __restrict__ xb, const char* ws,
                                      const float (&w2v)[8], const float (&b1v)[8],
                                      int lane, int l15, int lg)
{
    asm volatile("s_waitcnt vmcnt(%0)" :: "i"(N) : "memory");

    f32x4 acc[8];
    #pragma unroll
    for (int nf = 0; nf < 8; ++nf) acc[nf] = f32x4{0.f, 0.f, 0.f, 0.f};

    #pragma unroll
    for (int ks = 0; ks < 4; ++ks) {
        // row l15, floats [ks*32 + lg*8, +8): units (j = ks*2+(lg>>1), q=(lg&1)*2, q+1)
        const int o = ks * 512 + (lg >> 1) * 256 + (lg & 1) * 128 + l15 * 4;
        float4 r0 = *reinterpret_cast<const float4*>(xb + o);
        float4 r1 = *reinterpret_cast<const float4*>(xb + o + 64);
        uint4 pa;
        pa.x = pack2(r0.x, r0.y);
        pa.y = pack2(r0.z, r0.w);
        pa.z = pack2(r1.x, r1.y);
        pa.w = pack2(r1.z, r1.w);
        bf16x8 a = __builtin_bit_cast(bf16x8, pa);
        const int kbyte = ks * 64 + lg * 16;
        #pragma unroll
        for (int nf = 0; nf < 8; ++nf) {
            int n = nf * 16 + l15;
            bf16x8 b = *reinterpret_cast<const bf16x8*>(
                ws + n * 256 + (kbyte ^ ((n & 7) << 4)));
            acc[nf] = __builtin_amdgcn_mfma_f32_16x16x32_bf16(a, b, acc[nf], 0, 0, 0);
        }
    }

    float part[4] = {0.f, 0.f, 0.f, 0.f};
    #pragma unroll
    for (int nf = 0; nf < 8; ++nf)
        #pragma unroll
        for (int j = 0; j < 4; ++j)
            part[j] += fmaxf(acc[nf][j] + b1v[nf], 0.f) * w2v[nf];
    #pragma unroll
    for (int off = 8; off >= 1; off >>= 1)
        #pragma unroll
        for (int j = 0; j < 4; ++j)
            part[j] += __shfl_xor(part[j], off, 64);
    // gather row L's value to lane L (L<16): row L held as part[L&3] of group L>>2
    int src = (lane & 12) << 2;
    float v0 = __shfl(part[0], src, 64);
    float v1 = __shfl(part[1], src, 64);
    float v2 = __shfl(part[2], src, 64);
    float v3 = __shfl(part[3], src, 64);
    int s = lane & 3;
    return (s == 0) ? v0 : (s == 1) ? v1 : (s == 2) ? v2 : v3;
}

__global__ __launch_bounds__(256, 2)
void fused_mlp_kernel(const float* __restrict__ X,
                      const float* __restrict__ W1,
                      const float* __restrict__ b1,
                      const float* __restrict__ W2,
                      const float* __restrict__ b2,
                      float* __restrict__ out)
{
    __shared__ alignas(16) short Ws[H_HID * F_IN];    // 32 KB: W1_c bf16 [n][k] swizzled
    __shared__ alignas(16) float Xs[4 * 3 * 2048];    // 96 KB: 4 waves x 3 bufs x 8 KB

    const int t    = threadIdx.x;
    const int lane = t & 63;
    const int wave = t >> 6;
    const int c    = blockIdx.x;          // channel-major (r3 best)
    const int m0   = blockIdx.y * ROWS;
    const int l15  = lane & 15;
    const int lg   = lane >> 4;

    char*  ws    = reinterpret_cast<char*>(Ws);
    float* slice = &Xs[wave * 3 * 2048];
    float *bu0 = slice, *bu1 = slice + 2048, *bu2 = slice + 4096;

    // prefetch tiles 0..2 first: HBM latency hides under W1 staging
    issue_tile(X, m0 + (0 * 4 + wave) * 16, c, lane, bu0);
    issue_tile(X, m0 + (1 * 4 + wave) * 16, c, lane, bu1);
    issue_tile(X, m0 + (2 * 4 + wave) * 16, c, lane, bu2);

    // ---- stage W1_c transposed to [n][k]: coalesced along n ----
    {
        const int n  = t & 127;
        const int kh = (t >> 7) * 64;
        const float* wbase = W1 + (size_t)c * F_IN * H_HID + n;
        #pragma unroll
        for (int kk = 0; kk < 64; kk += 8) {
            float f[8];
            #pragma unroll
            for (int j = 0; j < 8; ++j)
                f[j] = wbase[(size_t)(kh + kk + j) * H_HID];
            uint4 p;
            p.x = pack2(f[0], f[1]);
            p.y = pack2(f[2], f[3]);
            p.z = pack2(f[4], f[5]);
            p.w = pack2(f[6], f[7]);
            int byte = ((kh + kk) * 2) ^ ((n & 7) << 4);
            *reinterpret_cast<uint4*>(ws + n * 256 + byte) = p;
        }
    }

    float w2v[8], b1v[8];
    #pragma unroll
    for (int nf = 0; nf < 8; ++nf) {
        w2v[nf] = W2[c * H_HID + nf * 16 + l15];
        b1v[nf] = b1[c * H_HID + nf * 16 + l15];
    }
    const float b2c = b2[c];

    __syncthreads();   // Ws ready (drains vmcnt once; tiles 0-2 land here too)

    // ---- main loop: no barriers, per-wave counted-vmcnt pipeline ----
    // vm ops/round: 8 tile loads + 1 atomic. Tile sc retired <=> vmcnt <= 19
    // (atomic + 2x(8 loads + atomic) younger); use 17 for 2 slack.
    #pragma unroll 1
    for (int sc = 0; sc < NSUB - 3; ++sc) {   // 0..12, issue sc+3 = 3..15
        const int rbase = m0 + (sc * 4 + wave) * 16;
        float val = compute_round<17>(bu0, ws, w2v, b1v, lane, l15, lg);
        issue_tile(X, m0 + ((sc + 3) * 4 + wave) * 16, c, lane, bu0);
        if (lane < 16) atomicAdd(&out[rbase + lane], val + b2c);
        float* tmp = bu0; bu0 = bu1; bu1 = bu2; bu2 = tmp;
    }
    {   // sc = 13: no issue; younger = 19 -> N=17
        const int rbase = m0 + (13 * 4 + wave) * 16;
        float val = compute_round<17>(bu0, ws, w2v, b1v, lane, l15, lg);
        if (lane < 16) atomicAdd(&out[rbase + lane], val + b2c);
        float* tmp = bu0; bu0 = bu1; bu1 = bu2; bu2 = tmp;
    }
    {   // sc = 14: younger = 3 atomics + 8 loads = 11 -> N=9
        const int rbase = m0 + (14 * 4 + wave) * 16;
        float val = compute_round<9>(bu0, ws, w2v, b1v, lane, l15, lg);
        if (lane < 16) atomicAdd(&out[rbase + lane], val + b2c);
        float* tmp = bu0; bu0 = bu1; bu1 = bu2; bu2 = tmp;
    }
    {   // sc = 15: younger = 3 atomics -> N=1
        const int rbase = m0 + (15 * 4 + wave) * 16;
        float val = compute_round<1>(bu0, ws, w2v, b1v, lane, l15, lg);
        if (lane < 16) atomicAdd(&out[rbase + lane], val + b2c);
    }
}

extern "C" void kernel_launch(void* const* d_in, const int* in_sizes, int n_in,
                              void* d_out, int out_size, void* d_ws, size_t ws_size,
                              hipStream_t stream) {
    const float* X  = (const float*)d_in[0];   // [B, C, F]
    const float* W1 = (const float*)d_in[1];   // [C, F, H]
    const float* b1 = (const float*)d_in[2];   // [C, H]
    const float* W2 = (const float*)d_in[3];   // [C, H]
    const float* b2 = (const float*)d_in[4];   // [C]
    float* out = (float*)d_out;                // [B]

    // atomics accumulate into out -> must zero it every call (d_out is poisoned)
    hipMemsetAsync(out, 0, (size_t)out_size * sizeof(float), stream);

    dim3 grid(C_CH, B_TOT / ROWS);   // (64, 16) = 1024 blocks, channel-major
    fused_mlp_kernel<<<grid, dim3(256), 0, stream>>>(X, W1, b1, W2, b2, out);
}

// Round 9
// 105.356 us; speedup vs baseline: 2.9618x; 1.2344x over previous
//
#include <hip/hip_runtime.h>
#include <hip/hip_bf16.h>

#define B_TOT 16384
#define C_CH  64
#define F_IN  128
#define H_HID 128
#define CG    4            // channels per block (2KB contiguous per row-chunk)
#define TROWS 16           // batch rows per tile
#define NSUB  64           // tiles per block -> 1024 rows
#define ROWS  (NSUB * TROWS)

using f32x4  = __attribute__((ext_vector_type(4))) float;
using bf16x8 = __attribute__((ext_vector_type(8))) short;

__device__ inline unsigned pack2(float a, float b) {
    unsigned short lo = __builtin_bit_cast(unsigned short, __float2bfloat16(a));
    unsigned short hi = __builtin_bit_cast(unsigned short, __float2bfloat16(b));
    return (unsigned)lo | ((unsigned)hi << 16);
}

// async global->LDS, 16B/lane; LDS dest = wave-uniform base + lane*16 (HW rule)
__device__ inline void gld_lds16(const float* g, float* l) {
    __builtin_amdgcn_global_load_lds(
        (const __attribute__((address_space(1))) void*)g,
        (__attribute__((address_space(3))) void*)l, 16, 0, 0);
}

// Stage tile: 16 rows x 2KB (4 adjacent channels). Each instr reads a fully
// CONTIGUOUS 1KB half-chunk (the DRAM-page fix). Source-side XOR swizzle
// (unit ^ (row&7), within the 1KB half) so later ds_read_b128 is bank-balanced;
// LDS layout: float off = r*512 + h*256 + unit*4, unit holds global unit^(r&7).
__device__ inline void issue_tile(const float* __restrict__ X, size_t base0,
                                  int wave, int lane, float* buf) {
    #pragma unroll
    for (int q = 0; q < 2; ++q) {
        const int r = wave * 2 + q;                    // 8 waves x 2 rows = 16
        const float* rowp = X + base0 + (size_t)r * (C_CH * F_IN);
        const int sw = r & 7;
        #pragma unroll
        for (int h = 0; h < 2; ++h)
            gld_lds16(rowp + h * 256 + ((lane ^ sw) << 2),
                      buf + r * 512 + h * 256);
    }
}

// One round: wait own tile slice (counted vmcnt, never 0 mid-loop), barrier
// (all waves' slices in; 3-buf rotation makes one barrier overwrite-safe),
// then 16 MFMA with W(regs) as A, X(LDS) as B. Swapped operands => batch row
// is lane-local: epilogue = in-lane relu-dot + 2 shuffles only.
template<int N>
__device__ inline float compute_round(const float* __restrict__ xb,
                                      const bf16x8 (&wf)[4][4],
                                      const f32x4 (&w2c)[4],
                                      const f32x4 (&b1c)[4],
                                      int l15, int lg, int ch)
{
    asm volatile("s_waitcnt vmcnt(%0)" :: "i"(N) : "memory");
    __builtin_amdgcn_s_barrier();

    f32x4 acc[4];
    #pragma unroll
    for (int nf = 0; nf < 4; ++nf) acc[nf] = b1c[nf];   // b1 rides as C-init

    const int sw = l15 & 7;
    const int rb = l15 * 512 + (ch >> 1) * 256;
    #pragma unroll
    for (int ks = 0; ks < 4; ++ks) {
        const int u6 = (ch & 1) * 32 + ks * 8 + lg * 2;
        float4 r0 = *reinterpret_cast<const float4*>(xb + rb + ((u6 ^ sw) << 2));
        float4 r1 = *reinterpret_cast<const float4*>(xb + rb + (((u6 + 1) ^ sw) << 2));
        uint4 px;
        px.x = pack2(r0.x, r0.y);
        px.y = pack2(r0.z, r0.w);
        px.z = pack2(r1.x, r1.y);
        px.w = pack2(r1.z, r1.w);
        bf16x8 xfrag = __builtin_bit_cast(bf16x8, px);
        #pragma unroll
        for (int nf = 0; nf < 4; ++nf)
            acc[nf] = __builtin_amdgcn_mfma_f32_16x16x32_bf16(
                wf[nf][ks], xfrag, acc[nf], 0, 0, 0);   // W as A, X as B
    }

    // acc[nf][j]: batch row = l15 (lane-local), h = hh*64 + nf*16 + lg*4 + j
    float val = 0.f;
    #pragma unroll
    for (int nf = 0; nf < 4; ++nf)
        #pragma unroll
        for (int j = 0; j < 4; ++j)
            val += fmaxf(acc[nf][j], 0.f) * w2c[nf][j];
    val += __shfl_xor(val, 16, 64);   // sum the 4 lg-groups (h quarters)
    val += __shfl_xor(val, 32, 64);
    return val;
}

__global__ __launch_bounds__(512, 2)
void fused_mlp_kernel(const float* __restrict__ X,
                      const float* __restrict__ W1,
                      const float* __restrict__ b1,
                      const float* __restrict__ W2,
                      const float* __restrict__ b2,
                      float* __restrict__ out)
{
    __shared__ alignas(16) float Xs[3 * TROWS * 512];   // 3 bufs x 32KB = 96KB

    const int t    = threadIdx.x;
    const int lane = t & 63;
    const int wave = t >> 6;            // 8 waves: role = (ch, h-half)
    const int l15  = lane & 15;
    const int lg   = lane >> 4;
    const int ch   = wave & 3;
    const int hh   = wave >> 2;

    const int c0 = blockIdx.x * CG;
    const int c  = c0 + ch;
    const int m0 = blockIdx.y * ROWS;

    float* bu0 = Xs;
    float* bu1 = Xs + TROWS * 512;
    float* bu2 = Xs + 2 * TROWS * 512;

    // prefill 2 tiles first: their HBM latency hides under W-reg staging
    const size_t cbase = ((size_t)m0 * C_CH + c0) * F_IN;
    const size_t tstep = (size_t)TROWS * C_CH * F_IN;
    issue_tile(X, cbase, wave, lane, bu0);
    issue_tile(X, cbase + tstep, wave, lane, bu1);

    // ---- W1 fragments -> registers (64 VGPR): wave owns (channel, h-half) ----
    bf16x8 wf[4][4];
    {
        const float* wb = W1 + (size_t)c * F_IN * H_HID + hh * 64 + l15;
        #pragma unroll
        for (int nf = 0; nf < 4; ++nf)
            #pragma unroll
            for (int ks = 0; ks < 4; ++ks) {
                const int f0 = ks * 32 + lg * 8;
                float v[8];
                #pragma unroll
                for (int e = 0; e < 8; ++e)
                    v[e] = wb[(size_t)(f0 + e) * H_HID + nf * 16];
                uint4 p;
                p.x = pack2(v[0], v[1]);
                p.y = pack2(v[2], v[3]);
                p.z = pack2(v[4], v[5]);
                p.w = pack2(v[6], v[7]);
                wf[nf][ks] = __builtin_bit_cast(bf16x8, p);
            }
    }
    f32x4 w2c[4], b1c[4];
    #pragma unroll
    for (int nf = 0; nf < 4; ++nf) {
        const int ho = c * H_HID + hh * 64 + nf * 16 + lg * 4;
        w2c[nf] = *reinterpret_cast<const f32x4*>(W2 + ho);
        b1c[nf] = *reinterpret_cast<const f32x4*>(b1 + ho);
    }
    const float b2c = (hh == 0) ? b2[c] : 0.f;   // b2[c] added once per channel

    // ---- main loop: 1 barrier + counted vmcnt per round, 3-buf rotation ----
    // vm ops/round/wave: 4 gld_lds + 1 atomic. Younger than tile sc's loads:
    // {atomic(sc-2), 4 loads(sc+1), atomic(sc-1)} = 6 program-order, >=5 under
    // any reorder -> N=5 safe. Peeled last iter: N=1.
    #pragma unroll 1
    for (int sc = 0; sc < NSUB - 1; ++sc) {
        float val = compute_round<5>(bu0, wf, w2c, b1c, l15, lg, ch);
        if (sc + 2 < NSUB)
            issue_tile(X, cbase + (size_t)(sc + 2) * tstep, wave, lane, bu2);
        if (lane < 16) atomicAdd(&out[m0 + sc * TROWS + lane], val + b2c);
        float* tmp = bu0; bu0 = bu1; bu1 = bu2; bu2 = tmp;
    }
    {
        float val = compute_round<1>(bu0, wf, w2c, b1c, l15, lg, ch);
        if (lane < 16) atomicAdd(&out[m0 + (NSUB - 1) * TROWS + lane], val + b2c);
    }
}

extern "C" void kernel_launch(void* const* d_in, const int* in_sizes, int n_in,
                              void* d_out, int out_size, void* d_ws, size_t ws_size,
                              hipStream_t stream) {
    const float* X  = (const float*)d_in[0];   // [B, C, F]
    const float* W1 = (const float*)d_in[1];   // [C, F, H]
    const float* b1 = (const float*)d_in[2];   // [C, H]
    const float* W2 = (const float*)d_in[3];   // [C, H]
    const float* b2 = (const float*)d_in[4];   // [C]
    float* out = (float*)d_out;                // [B]

    // atomics accumulate into out -> must zero it every call (d_out is poisoned)
    hipMemsetAsync(out, 0, (size_t)out_size * sizeof(float), stream);

    dim3 grid(C_CH / CG, B_TOT / ROWS);   // (16, 16) = 256 blocks = 1/CU
    fused_mlp_kernel<<<grid, dim3(512), 0, stream>>>(X, W1, b1, W2, b2, out);
}